// Round 4
// baseline (158.397 us; speedup 1.0000x reference)
//
#include <hip/hip_runtime.h>
#include <hip/hip_bf16.h>

// phi = exp(-d2/(2*ls^2)) = exp2(-S2*d2), S2 = 1/(2*0.3^2*ln2) = 8.014973
// Expanded: exp2(2*S2*(x.c) - S2*|x|^2 - S2*|c|^2)
//   per-center pack: a = (K2*cx, K2*cy, K2*cz, -S2*|c|^2), b = (cu,cv,cw,0)
//   per-lane  PX = -S2*|x|^2  (exponent always <= 0 -> exp2 in (0,1])
#define S2 8.014973f
#define K2 16.029946f
#define NCHUNK 21
#define PER 162                 // even chunk size; NCHUNK*PER = 3402 >= M=3375
#define MPAD (NCHUNK * PER)     // dummy centers have zero coeffs -> contribute 0

typedef float f16v __attribute__((ext_vector_type(16)));

__global__ void rbf_prep_kernel(const float* __restrict__ centers,
                                const float* __restrict__ cu,
                                const float* __restrict__ cv,
                                const float* __restrict__ cw,
                                float4* __restrict__ cpack, int M) {
    int m = blockIdx.x * 256 + threadIdx.x;
    if (m < MPAD + 2) {  // +2: prefetch overshoot target, zeroed
        float4 a = {0.f, 0.f, 0.f, 0.f}, b = {0.f, 0.f, 0.f, 0.f};
        if (m < M) {
            float cx = centers[3 * m + 0];
            float cy = centers[3 * m + 1];
            float cz = centers[3 * m + 2];
            a.x = K2 * cx;
            a.y = K2 * cy;
            a.z = K2 * cz;
            a.w = -S2 * (cx * cx + cy * cy + cz * cz);
            b.x = cu[m];
            b.y = cv[m];
            b.z = cw[m];
        }
        cpack[2 * m + 0] = a;
        cpack[2 * m + 1] = b;
    }
}

// Wave-task pool: task = (tile of 256 points) x (chunk of 162 centers).
// 391 tiles x 21 chunks = 8211 tasks over 8192 waves -> ~1 task/wave, balanced.
// 4 points/lane amortizes each center over 256 pairs (32 VALU per center-wave
// = 0.125 wave-instr/pair). Centers fetched via s_load_dwordx16 (2 centers per
// scalar load, software-pipelined) -> zero vector-pipe issue cost for staging;
// R3 showed the limiter is the per-SIMD issue port (VALUBusy flat at 57%
// across 40->60% occupancy), so every deleted vector instruction is time.
__global__ __launch_bounds__(256) void rbf_main_kernel(
    const float* __restrict__ x, const float4* __restrict__ cpack,
    float* __restrict__ out, int N, int NT, int ntask) {
    const int lane = threadIdx.x & 63;
    const int wid =
        __builtin_amdgcn_readfirstlane(blockIdx.x * 4 + (threadIdx.x >> 6));
    const int nwaves = gridDim.x * 4;

    for (int task = wid; task < ntask; task += nwaves) {
        const int tile = task % NT;   // uniform
        const int chunk = task / NT;  // uniform

        float X[4], Y[4], Z[4], PX[4];
        int p[4];
#pragma unroll
        for (int q = 0; q < 4; ++q) {
            int pp = tile * 256 + q * 64 + lane;
            p[q] = pp;
            float a = 0.f, b = 0.f, c = 0.f;
            if (pp < N) {
                a = x[3 * pp + 0];
                b = x[3 * pp + 1];
                c = x[3 * pp + 2];
            }
            X[q] = a;
            Y[q] = b;
            Z[q] = c;
            PX[q] = -S2 * (a * a + b * b + c * c);
        }
        float AU[4] = {0.f, 0.f, 0.f, 0.f};
        float AV[4] = {0.f, 0.f, 0.f, 0.f};
        float AW[4] = {0.f, 0.f, 0.f, 0.f};

        uint64_t ap = (uint64_t)(const void*)(cpack + 2 * (size_t)chunk * PER);
        f16v cc, cn;
        asm volatile("s_load_dwordx16 %0, %1, 0x0" : "=s"(cc) : "s"(ap));
        asm volatile("s_waitcnt lgkmcnt(0)" : "+s"(cc));
#pragma unroll 1
        for (int it = 0; it < PER / 2; ++it) {
            ap += 64;
            // prefetch next 2 centers (last iter overshoots into zeroed pad)
            asm volatile("s_load_dwordx16 %0, %1, 0x0" : "=s"(cn) : "s"(ap));
#pragma unroll
            for (int q = 0; q < 4; ++q) {
                float e0 = fmaf(X[q], cc[0],
                           fmaf(Y[q], cc[1],
                           fmaf(Z[q], cc[2], PX[q] + cc[3])));
                float f0 = __builtin_amdgcn_exp2f(e0);
                AU[q] = fmaf(f0, cc[4], AU[q]);
                AV[q] = fmaf(f0, cc[5], AV[q]);
                AW[q] = fmaf(f0, cc[6], AW[q]);
                float e1 = fmaf(X[q], cc[8],
                           fmaf(Y[q], cc[9],
                           fmaf(Z[q], cc[10], PX[q] + cc[11])));
                float f1 = __builtin_amdgcn_exp2f(e1);
                AU[q] = fmaf(f1, cc[12], AU[q]);
                AV[q] = fmaf(f1, cc[13], AV[q]);
                AW[q] = fmaf(f1, cc[14], AW[q]);
            }
            // compute above (~128 cyc) covers the SMEM latency; lgkmcnt(0) is
            // required (SMEM returns can be out of order -> partial waits unsafe)
            asm volatile("s_waitcnt lgkmcnt(0)" : "+s"(cn));
            cc = cn;
        }

        if (chunk == 0) {  // fold base field x*(1-||x||) once per point
#pragma unroll
            for (int q = 0; q < 4; ++q) {
                float g = 1.f - sqrtf(X[q] * X[q] + Y[q] * Y[q] + Z[q] * Z[q]);
                AU[q] += X[q] * g;
                AV[q] += Y[q] * g;
                AW[q] += Z[q] * g;
            }
        }
#pragma unroll
        for (int q = 0; q < 4; ++q) {
            if (p[q] < N) {
                atomicAdd(&out[3 * p[q] + 0], AU[q]);
                atomicAdd(&out[3 * p[q] + 1], AV[q]);
                atomicAdd(&out[3 * p[q] + 2], AW[q]);
            }
        }
    }
}

extern "C" void kernel_launch(void* const* d_in, const int* in_sizes, int n_in,
                              void* d_out, int out_size, void* d_ws,
                              size_t ws_size, hipStream_t stream) {
    const float* x = (const float*)d_in[0];
    const float* centers = (const float*)d_in[1];
    const float* cu = (const float*)d_in[2];
    const float* cv = (const float*)d_in[3];
    const float* cw = (const float*)d_in[4];
    const int N = in_sizes[0] / 3;
    const int M = in_sizes[1] / 3;
    float4* cpack = (float4*)d_ws;
    float* out = (float*)d_out;

    const int NT = (N + 255) / 256;       // 391
    const int ntask = NT * NCHUNK;        // 8211

    hipLaunchKernelGGL(rbf_prep_kernel, dim3((MPAD + 2 + 255) / 256), dim3(256),
                       0, stream, centers, cu, cv, cw, cpack, M);
    hipMemsetAsync(d_out, 0, (size_t)out_size * sizeof(float), stream);
    hipLaunchKernelGGL(rbf_main_kernel, dim3(2048), dim3(256), 0, stream, x,
                       cpack, out, N, NT, ntask);
}